// Round 1
// baseline (1481.328 us; speedup 1.0000x reference)
//
#include <hip/hip_runtime.h>

#define NN 100000
#define NE 1600000
#define D 64
#define NR 8

__device__ __forceinline__ float lane_bcast(float v, int k) {
    return __uint_as_float(__builtin_amdgcn_readlane(__float_as_uint(v), k));
}

__global__ void zero_kernel(float* p, int n) {
    int i = blockIdx.x * blockDim.x + threadIdx.x;
    if (i < n) p[i] = 0.0f;
}

__global__ void count_kernel(const int* __restrict__ ei, const int* __restrict__ et,
                             float* __restrict__ cnt) {
    int e = blockIdx.x * blockDim.x + threadIdx.x;
    if (e >= NE) return;
    int r = et[e];
    int d = ei[NE + e];
    atomicAdd(&cnt[r * NN + d], 1.0f);
}

__global__ void inv_kernel(float* __restrict__ cnt, int n) {
    int i = blockIdx.x * blockDim.x + threadIdx.x;
    if (i < n) cnt[i] = 1.0f / fmaxf(cnt[i], 1.0f);
}

// out[n][l] = bias[l] + sum_k x[n][k] * W_root[k][l]
__global__ void __launch_bounds__(256) root_kernel(
    const float* __restrict__ x, const float* __restrict__ Wr,
    const float* __restrict__ bias, float* __restrict__ out)
{
    const int lane = threadIdx.x & 63;
    const int wid = (blockIdx.x * blockDim.x + threadIdx.x) >> 6;
    const int nw = (gridDim.x * blockDim.x) >> 6;
    float Wc[D];
#pragma unroll
    for (int k = 0; k < D; ++k) Wc[k] = Wr[k * D + lane];
    float b = bias[lane];
    for (int n = wid; n < NN; n += nw) {
        float xv = x[n * D + lane];
        float acc = b;
#pragma unroll
        for (int k = 0; k < D; ++k)
            acc = fmaf(lane_bcast(xv, k), Wc[k], acc);
        out[n * D + lane] = acc;
    }
}

// per edge e of relation r: out[dst] += (x[src] @ W[r]) * invc[r][dst]
// wave-per-chunk, lane = output dim, W[r] column in 64 VGPRs, 8 relation passes
__global__ void __launch_bounds__(256) edge_kernel(
    const float* __restrict__ x, const int* __restrict__ ei,
    const int* __restrict__ et, const float* __restrict__ W,
    const float* __restrict__ invc, float* __restrict__ out)
{
    const int lane = threadIdx.x & 63;
    const int wid = (blockIdx.x * blockDim.x + threadIdx.x) >> 6;
    const int nw = (gridDim.x * blockDim.x) >> 6;
    const int chunk = (NE + nw - 1) / nw;
    const int e0 = wid * chunk;
    const int e1 = min(e0 + chunk, NE);
    if (e0 >= e1) return;

    for (int r = 0; r < NR; ++r) {
        float Wc[D];
#pragma unroll
        for (int k = 0; k < D; ++k) Wc[k] = W[(r * D + k) * D + lane];
        for (int e = e0; e < e1; ++e) {
            int t = et[e];            // wave-uniform value (same addr, broadcast)
            if (t != r) continue;
            int s = ei[e];
            int d = ei[NE + e];
            float xv = x[s * D + lane];
            float scale = invc[r * NN + d];
            float acc = 0.0f;
#pragma unroll
            for (int k = 0; k < D; ++k)
                acc = fmaf(lane_bcast(xv, k), Wc[k], acc);
            atomicAdd(&out[d * D + lane], acc * scale);
        }
    }
}

__global__ void relu_kernel(float* __restrict__ out, int n) {
    int i = blockIdx.x * blockDim.x + threadIdx.x;
    if (i < n) out[i] = fmaxf(out[i], 0.0f);
}

extern "C" void kernel_launch(void* const* d_in, const int* in_sizes, int n_in,
                              void* d_out, int out_size, void* d_ws, size_t ws_size,
                              hipStream_t stream) {
    const float* x    = (const float*)d_in[0];
    const int*   ei   = (const int*)d_in[1];   // [2, NE]
    const int*   et   = (const int*)d_in[2];   // [NE]
    const float* W    = (const float*)d_in[3]; // [NR, D, D]
    const float* Wr   = (const float*)d_in[4]; // [D, D]
    const float* bias = (const float*)d_in[5]; // [D]
    float* out = (float*)d_out;                // [NN, D]
    float* cnt = (float*)d_ws;                 // [NR * NN] counts -> inverses

    const int NCNT = NR * NN;

    zero_kernel<<<(NCNT + 255) / 256, 256, 0, stream>>>(cnt, NCNT);
    count_kernel<<<(NE + 255) / 256, 256, 0, stream>>>(ei, et, cnt);
    inv_kernel<<<(NCNT + 255) / 256, 256, 0, stream>>>(cnt, NCNT);
    root_kernel<<<1024, 256, 0, stream>>>(x, Wr, bias, out);
    edge_kernel<<<1024, 256, 0, stream>>>(x, ei, et, W, cnt, out);
    relu_kernel<<<(NN * D + 255) / 256, 256, 0, stream>>>(out, NN * D);
}

// Round 3
// 517.144 us; speedup vs baseline: 2.8644x; 2.8644x over previous
//
#include <hip/hip_runtime.h>

#define NN 100000
#define NE 1600000
#define D 64
#define NR 8
#define NTILES (NN / 16)   // 6250, exact

typedef short bf16x8 __attribute__((ext_vector_type(8)));
typedef float f32x4 __attribute__((ext_vector_type(4)));

// f32 -> bf16 (round-to-nearest-even), no NaN handling needed (finite inputs)
__device__ __forceinline__ short f2bf(float f) {
    unsigned u = __float_as_uint(f);
    unsigned r = (u + 0x7fffu + ((u >> 16) & 1u)) >> 16;
    return (short)r;
}

// One wave per edge: agg[r-rbase][dst][lane] += x[src][lane]; cnt[r][dst] += 1
__global__ void __launch_bounds__(256) scatter_kernel(
    const float* __restrict__ x, const int* __restrict__ ei,
    const int* __restrict__ et, float* __restrict__ agg,
    float* __restrict__ cnt, int rbase, int rlo, int rhi)
{
    const int lane = threadIdx.x & 63;
    int w = (blockIdx.x * blockDim.x + threadIdx.x) >> 6;
    int nw = (gridDim.x * blockDim.x) >> 6;
    for (int e = w; e < NE; e += nw) {
        int r = et[e];
        if (r < rlo || r >= rhi) continue;
        int s = ei[e];
        int d = ei[NE + e];
        float xv = x[(size_t)s * D + lane];
        atomicAdd(&agg[((size_t)(r - rbase) * NN + d) * D + lane], xv);
        if (lane == 0) atomicAdd(&cnt[(size_t)r * NN + d], 1.0f);
    }
}

// Fused: out[tile nodes] (+)= sum_{r} (agg[r]*inv(cnt[r])) @ W[r]  (+ x@Wr + bias, + relu)
// One wave per 16-node tile, 4 waves/block. MFMA 16x16x32 bf16.
// A: m=lane&15 (node), k=(lane>>4)*8+j (+32 for ks=1)
// B: n=lane&15 (outdim), same k mapping; D: col=lane&15 (outdim), row=(lane>>4)*4+i (node)
__global__ void __launch_bounds__(256) mfma_kernel(
    const float* __restrict__ x, const float* __restrict__ agg,
    const float* __restrict__ cnt, const float* __restrict__ W,
    const float* __restrict__ Wr, const float* __restrict__ bias,
    float* __restrict__ out, int rbase, int rcount,
    int withRoot, int withRelu, int initOut)
{
    __shared__ float Wlds[D * 65];  // +1 pad: kills 4-way bank conflict
    const int tid = threadIdx.x;
    const int lane = tid & 63;
    const int wv = tid >> 6;
    int tile = blockIdx.x * 4 + wv;
    const bool active = tile < NTILES;
    if (!active) tile = NTILES - 1;
    const int ncol = lane & 15;
    const int krow = (lane >> 4) * 8;
    const int n_a = tile * 16 + ncol;              // A-row node for this lane
    const int n_c = tile * 16 + (lane >> 4) * 4;   // C-row node base for this lane

    f32x4 acc[4];
#pragma unroll
    for (int nt = 0; nt < 4; ++nt) {
        if (initOut) {
#pragma unroll
            for (int i = 0; i < 4; ++i)
                acc[nt][i] = out[(size_t)(n_c + i) * D + nt * 16 + ncol];
        } else {
#pragma unroll
            for (int i = 0; i < 4; ++i) acc[nt][i] = 0.0f;
        }
    }

    const int niter = rcount + (withRoot ? 1 : 0);
    for (int it = 0; it < niter; ++it) {
        const bool isRoot = (it == rcount);
        const int rr = rbase + it;
        const float* Wsrc = isRoot ? Wr : (W + (size_t)rr * D * D);

        __syncthreads();  // protect previous iteration's LDS reads
#pragma unroll
        for (int q = 0; q < 4; ++q) {
            int v = tid + q * 256;               // float4 index, 1024 total
            float4 f = ((const float4*)Wsrc)[v];
            int row = v >> 4, col = (v & 15) * 4;
            float* p = &Wlds[row * 65 + col];
            p[0] = f.x; p[1] = f.y; p[2] = f.z; p[3] = f.w;
        }
        __syncthreads();

        float sc = 1.0f;
        const float* Asrc;
        if (isRoot) {
            Asrc = x;
        } else {
            float c = cnt[(size_t)rr * NN + n_a];
            sc = 1.0f / fmaxf(c, 1.0f);
            Asrc = agg + (size_t)it * NN * D;   // it == rr - rbase for non-root
        }
        const float* arow = Asrc + (size_t)n_a * D + krow;

#pragma unroll
        for (int ks = 0; ks < 2; ++ks) {
            float4 lo = *(const float4*)(arow + ks * 32);
            float4 hi = *(const float4*)(arow + ks * 32 + 4);
            bf16x8 af;
            af[0] = f2bf(lo.x * sc); af[1] = f2bf(lo.y * sc);
            af[2] = f2bf(lo.z * sc); af[3] = f2bf(lo.w * sc);
            af[4] = f2bf(hi.x * sc); af[5] = f2bf(hi.y * sc);
            af[6] = f2bf(hi.z * sc); af[7] = f2bf(hi.w * sc);
#pragma unroll
            for (int nt = 0; nt < 4; ++nt) {
                bf16x8 bf;
#pragma unroll
                for (int j = 0; j < 8; ++j)
                    bf[j] = f2bf(Wlds[(ks * 32 + krow + j) * 65 + nt * 16 + ncol]);
                acc[nt] = __builtin_amdgcn_mfma_f32_16x16x32_bf16(af, bf, acc[nt], 0, 0, 0);
            }
        }
    }

#pragma unroll
    for (int nt = 0; nt < 4; ++nt) {
        float bv = withRoot ? bias[nt * 16 + ncol] : 0.0f;
#pragma unroll
        for (int i = 0; i < 4; ++i) {
            float vv = acc[nt][i] + bv;
            if (withRelu) vv = fmaxf(vv, 0.0f);
            acc[nt][i] = vv;
        }
    }
    if (active) {
#pragma unroll
        for (int nt = 0; nt < 4; ++nt)
#pragma unroll
            for (int i = 0; i < 4; ++i)
                out[(size_t)(n_c + i) * D + nt * 16 + ncol] = acc[nt][i];
    }
}

extern "C" void kernel_launch(void* const* d_in, const int* in_sizes, int n_in,
                              void* d_out, int out_size, void* d_ws, size_t ws_size,
                              hipStream_t stream) {
    const float* x    = (const float*)d_in[0];
    const int*   ei   = (const int*)d_in[1];   // [2, NE]
    const int*   et   = (const int*)d_in[2];   // [NE]
    const float* W    = (const float*)d_in[3]; // [NR, D, D]
    const float* Wr   = (const float*)d_in[4]; // [D, D]
    const float* bias = (const float*)d_in[5]; // [D]
    float* out = (float*)d_out;                // [NN, D]

    const size_t NCNT = (size_t)NR * NN;                   // counts, f32
    float* cnt = (float*)d_ws;
    float* agg = cnt + NCNT;

    const size_t needFused = (NCNT + (size_t)NR * NN * D) * 4;  // ~208 MB
    const size_t needLoop  = (NCNT + (size_t)NN * D) * 4;       // ~28.8 MB

    const int mfmaBlocks = (NTILES + 3) / 4;  // 1563

    if (ws_size >= needFused) {
        hipMemsetAsync(d_ws, 0, needFused, stream);
        scatter_kernel<<<2048, 256, 0, stream>>>(x, ei, et, agg, cnt, 0, 0, NR);
        mfma_kernel<<<mfmaBlocks, 256, 0, stream>>>(
            x, agg, cnt, W, Wr, bias, out,
            /*rbase=*/0, /*rcount=*/NR, /*withRoot=*/1, /*withRelu=*/1, /*initOut=*/0);
    } else {
        // 8-pass loop mode: agg buffer [NN][D] reused per relation
        hipMemsetAsync(cnt, 0, NCNT * 4, stream);
        for (int r = 0; r < NR; ++r) {
            hipMemsetAsync(agg, 0, (size_t)NN * D * 4, stream);
            scatter_kernel<<<2048, 256, 0, stream>>>(x, ei, et, agg, cnt, r, r, r + 1);
            mfma_kernel<<<mfmaBlocks, 256, 0, stream>>>(
                x, agg, cnt, W, Wr, bias, out,
                /*rbase=*/r, /*rcount=*/1,
                /*withRoot=*/(r == 0) ? 1 : 0,
                /*withRelu=*/(r == NR - 1) ? 1 : 0,
                /*initOut=*/(r > 0) ? 1 : 0);
        }
    }
}